// Round 7
// baseline (4378.429 us; speedup 1.0000x reference)
//
#include <hip/hip_runtime.h>
#include <math.h>

#define H 64
#define SEQ_T 1024
#define BATCH 512
#define NTHR 128            // 2 waves: thread = (j = 32*wv + jl, ks = lane>>5)
#define NBLK BATCH          // 1 block = 1 batch row; 512 blocks = 2 blocks/CU

__device__ __forceinline__ float sigmoid_f(float v) {
    return 1.0f / (1.0f + __expf(-v));
}

// overflow-safe tanh: exp overflow -> inf -> 2/inf = 0 -> t=1
__device__ __forceinline__ float tanh_f(float v) {
    float ax = fabsf(v);
    float e = __expf(2.0f * ax);
    float t = 1.0f - 2.0f / (e + 1.0f);
    return copysignf(t, v);
}

// Barrier that drains ONLY LDS ops (leaves global prefetch loads / act stores
// in flight across the barrier; they retire FIFO at their vmcnt use points).
#define LDS_BARRIER() asm volatile("s_waitcnt lgkmcnt(0)\n\ts_barrier" ::: "memory")

#define FMA_H(hv, q)                                                            \
    hr = fmaf((hv).x, wHv[0][q].x, hr); hr = fmaf((hv).y, wHv[0][q].y, hr);     \
    hr = fmaf((hv).z, wHv[0][q].z, hr); hr = fmaf((hv).w, wHv[0][q].w, hr);     \
    hz = fmaf((hv).x, wHv[1][q].x, hz); hz = fmaf((hv).y, wHv[1][q].y, hz);     \
    hz = fmaf((hv).z, wHv[1][q].z, hz); hz = fmaf((hv).w, wHv[1][q].w, hz);     \
    hn = fmaf((hv).x, wHv[2][q].x, hn); hn = fmaf((hv).y, wHv[2][q].y, hn);     \
    hn = fmaf((hv).z, wHv[2][q].z, hn); hn = fmaf((hv).w, wHv[2][q].w, hn);

#define FMA_X(xv, q)                                                            \
    ar = fmaf((xv).x, wIv[0][q].x, ar); ar = fmaf((xv).y, wIv[0][q].y, ar);     \
    ar = fmaf((xv).z, wIv[0][q].z, ar); ar = fmaf((xv).w, wIv[0][q].w, ar);     \
    az = fmaf((xv).x, wIv[1][q].x, az); az = fmaf((xv).y, wIv[1][q].y, az);     \
    az = fmaf((xv).z, wIv[1][q].z, az); az = fmaf((xv).w, wIv[1][q].w, az);     \
    an = fmaf((xv).x, wIv[2][q].x, an); an = fmaf((xv).y, wIv[2][q].y, an);     \
    an = fmaf((xv).z, wIv[2][q].z, an); an = fmaf((xv).w, wIv[2][q].w, an);

// One GRU timestep. PR/PW: compile-time LDS buffer indices. X0..X7: this
// step's x regs (32 k-slice); reloaded for t+2 after consumption (depth-2).
// MODE: 0 = layer0 (x K=5, store), 1 = mid (store), 2 = last (no store).
#define GRU_STEP(X0, X1, X2, X3, X4, X5, X6, X7, PR, PW, TCUR, PPF)             \
  {                                                                             \
    float4 h0 = *(const float4*)(&hbuf[PR][k0]);                                \
    float4 h1 = *(const float4*)(&hbuf[PR][k0 + 4]);                            \
    float4 h2 = *(const float4*)(&hbuf[PR][k0 + 8]);                            \
    float4 h3 = *(const float4*)(&hbuf[PR][k0 + 12]);                           \
    float4 h4 = *(const float4*)(&hbuf[PR][k0 + 16]);                           \
    float4 h5 = *(const float4*)(&hbuf[PR][k0 + 20]);                           \
    float4 h6 = *(const float4*)(&hbuf[PR][k0 + 24]);                           \
    float4 h7 = *(const float4*)(&hbuf[PR][k0 + 28]);                           \
    float ar = 0.f, az = 0.f, an = 0.f, hr = 0.f, hz = 0.f, hn = 0.f;           \
    if (MODE == 0) {                                                            \
        /* input dim 5: ks==0 lanes hold k0..4 in X0,X1.x; weights padded 0 */  \
        FMA_X(X0, 0) FMA_X(X1, 1)                                               \
    } else {                                                                    \
        FMA_X(X0, 0) FMA_X(X1, 1) FMA_X(X2, 2) FMA_X(X3, 3)                     \
        FMA_X(X4, 4) FMA_X(X5, 5) FMA_X(X6, 6) FMA_X(X7, 7)                     \
    }                                                                           \
    FMA_H(h0, 0) FMA_H(h1, 1) FMA_H(h2, 2) FMA_H(h3, 3)                         \
    FMA_H(h4, 4) FMA_H(h5, 5) FMA_H(h6, 6) FMA_H(h7, 7)                         \
    /* depth-2 prefetch: reload just-consumed regs with x(t+2) */               \
    if (MODE == 0) {                                                            \
        if (ks == 0 && (TCUR) + 2 < SEQ_T) {                                    \
            X0 = make_float4(PPF[0], PPF[1], PPF[2], PPF[3]); X1.x = PPF[4];    \
        }                                                                       \
        PPF += 10;                                                              \
    } else {                                                                    \
        if ((TCUR) + 2 < SEQ_T) {                                               \
            const float4* pa_ = (const float4*)PPF;                             \
            X0 = pa_[0]; X1 = pa_[1]; X2 = pa_[2]; X3 = pa_[3];                 \
            X4 = pa_[4]; X5 = pa_[5]; X6 = pa_[6]; X7 = pa_[7];                 \
        }                                                                       \
        PPF += 2 * H;                                                           \
    }                                                                           \
    /* single-stage reduce across the 2 k-slices (xor 32) */                    \
    float sR = ar + hr, sZ = az + hz, sN = an, sH = hn;                         \
    sR += __shfl_xor(sR, 32, 64);                                               \
    sZ += __shfl_xor(sZ, 32, 64);                                               \
    sN += __shfl_xor(sN, 32, 64);                                               \
    sH += __shfl_xor(sH, 32, 64);                                               \
    float r = sigmoid_f(sR + bR);                                               \
    float z = sigmoid_f(sZ + bZ);                                               \
    float n = tanh_f(sN + bNi + r * (sH + bNh));                                \
    float hnew = fmaf(z, hprev - n, n); /* (1-z)*n + z*h */                     \
    hprev = hnew;                                                               \
    if (ks == 0) {                                                              \
        hbuf[PW][j] = hnew;                                                     \
        if (MODE < 2) *pSt = hnew;                                              \
    }                                                                           \
    pSt += H;                                                                   \
    LDS_BARRIER();                                                              \
  }

// Run one layer's full 1024-step recurrence. Weights already in VGPRs.
template <int MODE>
__device__ __forceinline__ float run_layer(
    const float* __restrict__ xin,   // MODE0: raw x row; else actb
    float* __restrict__ actb,        // store target (MODE<2)
    float (*hbuf)[H],
    const float4 (&wIv)[3][8], const float4 (&wHv)[3][8],
    float bR, float bZ, float bNi, float bNh,
    int j, int k0, int ks)
{
    float hprev = 0.0f;
    if (ks == 0) hbuf[0][j] = 0.0f;   // h0 = 0

    float4 xA0, xA1, xA2, xA3, xA4, xA5, xA6, xA7;
    float4 xB0, xB1, xB2, xB3, xB4, xB5, xB6, xB7;
    xA0 = xA1 = xA2 = xA3 = xA4 = xA5 = xA6 = xA7 = make_float4(0.f, 0.f, 0.f, 0.f);
    xB0 = xB1 = xB2 = xB3 = xB4 = xB5 = xB6 = xB7 = xA0;

    const float* pPFA;
    const float* pPFB;
    if (MODE == 0) {
        if (ks == 0) {
            const float* p0 = xin;        // t=0
            const float* p1 = xin + 5;    // t=1
            xA0 = make_float4(p0[0], p0[1], p0[2], p0[3]); xA1.x = p0[4];
            xB0 = make_float4(p1[0], p1[1], p1[2], p1[3]); xB1.x = p1[4];
        }
        pPFA = xin + 10;                  // t=2 (A holds even t)
        pPFB = xin + 15;                  // t=3 (B holds odd t)
    } else {
        const float4* a0 = (const float4*)(xin + 0 * H + k0);
        const float4* a1 = (const float4*)(xin + 1 * H + k0);
        xA0 = a0[0]; xA1 = a0[1]; xA2 = a0[2]; xA3 = a0[3];
        xA4 = a0[4]; xA5 = a0[5]; xA6 = a0[6]; xA7 = a0[7];
        xB0 = a1[0]; xB1 = a1[1]; xB2 = a1[2]; xB3 = a1[3];
        xB4 = a1[4]; xB5 = a1[5]; xB6 = a1[6]; xB7 = a1[7];
        pPFA = xin + 2 * H + k0;
        pPFB = xin + 3 * H + k0;
    }
    float* pSt = actb + j;

    // Layer boundary: FULL drain (prev layer's act stores -> this layer's
    // reads; hbuf init visibility). Once per layer — cheap.
    __syncthreads();

    for (int t = 0; t < SEQ_T; t += 2) {
        GRU_STEP(xA0, xA1, xA2, xA3, xA4, xA5, xA6, xA7, 0, 1, t,     pPFA)
        GRU_STEP(xB0, xB1, xB2, xB3, xB4, xB5, xB6, xB7, 1, 0, t + 1, pPFB)
    }
    return hprev;
}

__global__ __launch_bounds__(NTHR, 1) void gru_all_kernel(
    const float* __restrict__ x,
    const float* __restrict__ w_ih0, const float* __restrict__ w_hh0,
    const float* __restrict__ b_ih0, const float* __restrict__ b_hh0,
    const float* __restrict__ w_ih, const float* __restrict__ w_hh,
    const float* __restrict__ b_ih, const float* __restrict__ b_hh,
    const float* __restrict__ w_fc, const float* __restrict__ b_fc,
    float* __restrict__ out, float* __restrict__ act)
{
    __shared__ __align__(16) float hbuf[2][H];  // double-buffered hidden state
    __shared__ float partial[2];

    const int tid  = threadIdx.x;
    const int wv   = tid >> 6;        // wave 0..1
    const int lane = tid & 63;
    const int jl   = lane & 31;
    const int ks   = lane >> 5;       // k-slice 0..1 (k in [32ks, 32ks+32))
    const int j    = wv * 32 + jl;    // output h-index
    const int k0   = ks * 32;
    const int b    = blockIdx.x;

    float* __restrict__ actb = act + (size_t)b * (SEQ_T * H);
    const float* __restrict__ xb = x + (size_t)b * (SEQ_T * 5);

    float hlast = 0.0f;
    float4 wIv[3][8], wHv[3][8];

    for (int layer = 0; layer < 5; ++layer) {
        // ---- weight slices -> VGPRs, ONCE per layer ----
        {
            const float* whp = (layer == 0) ? w_hh0 : w_hh + (size_t)(layer - 1) * (192 * H);
            #pragma unroll
            for (int g = 0; g < 3; ++g) {
                const float4* row = (const float4*)(whp + (g * 64 + j) * H + k0);
                #pragma unroll
                for (int q = 0; q < 8; ++q) wHv[g][q] = row[q];
            }
            if (layer == 0) {
                #pragma unroll
                for (int g = 0; g < 3; ++g)
                    #pragma unroll
                    for (int q = 0; q < 8; ++q) wIv[g][q] = make_float4(0.f, 0.f, 0.f, 0.f);
                if (ks == 0) {
                    #pragma unroll
                    for (int g = 0; g < 3; ++g) {
                        const float* row = w_ih0 + (g * 64 + j) * 5;
                        wIv[g][0] = make_float4(row[0], row[1], row[2], row[3]);
                        wIv[g][1].x = row[4];   // k4; .yzw stay 0
                    }
                }
            } else {
                const float* wip = w_ih + (size_t)(layer - 1) * (192 * H);
                #pragma unroll
                for (int g = 0; g < 3; ++g) {
                    const float4* row = (const float4*)(wip + (g * 64 + j) * H + k0);
                    #pragma unroll
                    for (int q = 0; q < 8; ++q) wIv[g][q] = row[q];
                }
            }
        }

        // biases (r/z input+hidden pre-summed; n-gate parts stay separate)
        float bR, bZ, bNi, bNh;
        {
            const float* bip = (layer == 0) ? b_ih0 : b_ih + (layer - 1) * 192;
            const float* bhp = (layer == 0) ? b_hh0 : b_hh + (layer - 1) * 192;
            bR  = bip[j] + bhp[j];
            bZ  = bip[j + 64] + bhp[j + 64];
            bNi = bip[j + 128];
            bNh = bhp[j + 128];
        }

        if (layer == 0)
            hlast = run_layer<0>(xb, actb, hbuf, wIv, wHv, bR, bZ, bNi, bNh, j, k0, ks);
        else if (layer < 4)
            hlast = run_layer<1>(actb, actb, hbuf, wIv, wHv, bR, bZ, bNi, bNh, j, k0, ks);
        else
            hlast = run_layer<2>(actb, actb, hbuf, wIv, wHv, bR, bZ, bNi, bNh, j, k0, ks);
    }

    // ---- fused FC on last timestep: out[b] = h . w_fc + b_fc ----
    float v = (ks == 0) ? hlast * w_fc[j] : 0.0f;
    v += __shfl_xor(v, 1, 64);
    v += __shfl_xor(v, 2, 64);
    v += __shfl_xor(v, 4, 64);
    v += __shfl_xor(v, 8, 64);
    v += __shfl_xor(v, 16, 64);
    if (lane == 0) partial[wv] = v;
    __syncthreads();
    if (tid == 0) out[b] = partial[0] + partial[1] + b_fc[0];
}

extern "C" void kernel_launch(void* const* d_in, const int* in_sizes, int n_in,
                              void* d_out, int out_size, void* d_ws, size_t ws_size,
                              hipStream_t stream) {
    const float* x     = (const float*)d_in[0];
    const float* w_ih0 = (const float*)d_in[1];
    const float* w_hh0 = (const float*)d_in[2];
    const float* b_ih0 = (const float*)d_in[3];
    const float* b_hh0 = (const float*)d_in[4];
    const float* w_ih  = (const float*)d_in[5];
    const float* w_hh  = (const float*)d_in[6];
    const float* b_ih  = (const float*)d_in[7];
    const float* b_hh  = (const float*)d_in[8];
    const float* w_fc  = (const float*)d_in[9];
    const float* b_fc  = (const float*)d_in[10];
    float* out = (float*)d_out;
    float* act = (float*)d_ws;  // [BATCH][SEQ_T][H] fp32 = 128 MiB

    hipLaunchKernelGGL(gru_all_kernel, dim3(NBLK), dim3(NTHR), 0, stream,
                       x, w_ih0, w_hh0, b_ih0, b_hh0,
                       w_ih, w_hh, b_ih, b_hh, w_fc, b_fc, out, act);
}

// Round 8
// 3115.710 us; speedup vs baseline: 1.4053x; 1.4053x over previous
//
#include <hip/hip_runtime.h>
#include <math.h>

#define H 64
#define SEQ_T 1024
#define BATCH 512
#define NTHR 256            // 4 waves: thread = (j = 16*wv + jl, ks = lane>>4)
#define NBLK BATCH          // 1 block = 1 batch row; 512 blocks = 2 blocks/CU
#define LOG2E 1.44269504088896340736f

// Barrier that drains ONLY LDS ops (leaves global prefetch loads / act stores
// in flight across the barrier; they retire FIFO at their vmcnt use points).
#define LDS_BARRIER() asm volatile("s_waitcnt lgkmcnt(0)\n\ts_barrier" ::: "memory")

// Cross-lane reduce with zero per-step address math:
//   stage 1: xor-16 via ds_swizzle (mask in immediate, within 32-lane groups)
//   stage 2: xor-32 via ds_bpermute with hoisted byte address
#define XREDUCE(v)                                                              \
    v += __int_as_float(__builtin_amdgcn_ds_swizzle(__float_as_int(v), 0x401F));\
    v += __int_as_float(__builtin_amdgcn_ds_bpermute(bpaddr, __float_as_int(v)));

#define FMA_H(hv, q)                                                            \
    hr = fmaf((hv).x, wHv[0][q].x, hr); hr = fmaf((hv).y, wHv[0][q].y, hr);     \
    hr = fmaf((hv).z, wHv[0][q].z, hr); hr = fmaf((hv).w, wHv[0][q].w, hr);     \
    hz = fmaf((hv).x, wHv[1][q].x, hz); hz = fmaf((hv).y, wHv[1][q].y, hz);     \
    hz = fmaf((hv).z, wHv[1][q].z, hz); hz = fmaf((hv).w, wHv[1][q].w, hz);     \
    hn = fmaf((hv).x, wHv[2][q].x, hn); hn = fmaf((hv).y, wHv[2][q].y, hn);     \
    hn = fmaf((hv).z, wHv[2][q].z, hn); hn = fmaf((hv).w, wHv[2][q].w, hn);

#define FMA_X(xv, q)                                                            \
    ar = fmaf((xv).x, wIv[0][q].x, ar); ar = fmaf((xv).y, wIv[0][q].y, ar);     \
    ar = fmaf((xv).z, wIv[0][q].z, ar); ar = fmaf((xv).w, wIv[0][q].w, ar);     \
    az = fmaf((xv).x, wIv[1][q].x, az); az = fmaf((xv).y, wIv[1][q].y, az);     \
    az = fmaf((xv).z, wIv[1][q].z, az); az = fmaf((xv).w, wIv[1][q].w, az);     \
    an = fmaf((xv).x, wIv[2][q].x, an); an = fmaf((xv).y, wIv[2][q].y, an);     \
    an = fmaf((xv).z, wIv[2][q].z, an); an = fmaf((xv).w, wIv[2][q].w, an);

// One GRU timestep. PR/PW: compile-time LDS buffer indices. X*: this step's
// x regs; reloaded with x(t+2) after consumption (depth-2 prefetch).
// MODE: 0 = layer0 (x K=5, store), 1 = mid (store), 2 = last (no store).
#define GRU_STEP(X0, X1, X2, X3, PR, PW, TCUR, PPF)                             \
  {                                                                             \
    float4 h0 = *(const float4*)(&hbuf[PR][k0]);                                \
    float4 h1 = *(const float4*)(&hbuf[PR][k0 + 4]);                            \
    float4 h2 = *(const float4*)(&hbuf[PR][k0 + 8]);                            \
    float4 h3 = *(const float4*)(&hbuf[PR][k0 + 12]);                           \
    float ar = 0.f, az = 0.f, an = 0.f, hr = 0.f, hz = 0.f, hn = 0.f;           \
    if (MODE == 0) {                                                            \
        /* input dim 5: only ks==0 lanes hold nonzero x/weights */              \
        ar = fmaf(X0.x, wIv[0][0].x, ar); ar = fmaf(X0.y, wIv[0][0].y, ar);     \
        ar = fmaf(X0.z, wIv[0][0].z, ar); ar = fmaf(X0.w, wIv[0][0].w, ar);     \
        ar = fmaf(X1.x, wIv[0][1].x, ar);                                       \
        az = fmaf(X0.x, wIv[1][0].x, az); az = fmaf(X0.y, wIv[1][0].y, az);     \
        az = fmaf(X0.z, wIv[1][0].z, az); az = fmaf(X0.w, wIv[1][0].w, az);     \
        az = fmaf(X1.x, wIv[1][1].x, az);                                       \
        an = fmaf(X0.x, wIv[2][0].x, an); an = fmaf(X0.y, wIv[2][0].y, an);     \
        an = fmaf(X0.z, wIv[2][0].z, an); an = fmaf(X0.w, wIv[2][1].x, an);     \
        an = fmaf(X1.x, wIv[2][1].y, an);                                       \
    } else {                                                                    \
        FMA_X(X0, 0) FMA_X(X1, 1) FMA_X(X2, 2) FMA_X(X3, 3)                     \
    }                                                                           \
    FMA_H(h0, 0) FMA_H(h1, 1) FMA_H(h2, 2) FMA_H(h3, 3)                         \
    /* prefetch x for TCUR+2 into the just-consumed regs */                     \
    if (MODE == 0) {                                                            \
        if (ks == 0 && (TCUR) + 2 < SEQ_T) {                                    \
            X0 = make_float4(PPF[0], PPF[1], PPF[2], PPF[3]); X1.x = PPF[4];    \
        }                                                                       \
        PPF += 10;                                                              \
    } else {                                                                    \
        if ((TCUR) + 2 < SEQ_T) {                                               \
            const float4* pa_ = (const float4*)PPF;                             \
            X0 = pa_[0]; X1 = pa_[1]; X2 = pa_[2]; X3 = pa_[3];                 \
        }                                                                       \
        PPF += 2 * H;                                                           \
    }                                                                           \
    float sR = ar + hr, sZ = az + hz, sN = an, sH = hn;                         \
    XREDUCE(sR) XREDUCE(sZ) XREDUCE(sN) XREDUCE(sH)                             \
    /* gates via raw v_exp/v_rcp (1-ulp class; threshold 1.37e-3) */            \
    float r = __builtin_amdgcn_rcpf(                                            \
        1.0f + __builtin_amdgcn_exp2f((sR + bR) * -LOG2E));                     \
    float z = __builtin_amdgcn_rcpf(                                            \
        1.0f + __builtin_amdgcn_exp2f((sZ + bZ) * -LOG2E));                     \
    float u_ = sN + bNi + r * (sH + bNh);                                       \
    float e2_ = __builtin_amdgcn_exp2f(fabsf(u_) * (2.0f * LOG2E));             \
    float t_ = fmaf(-2.0f, __builtin_amdgcn_rcpf(e2_ + 1.0f), 1.0f);            \
    float n = copysignf(t_, u_);                                                \
    float hnew = fmaf(z, hprev - n, n); /* (1-z)*n + z*h */                     \
    hprev = hnew;                                                               \
    if (ks == 0) {                                                              \
        hbuf[PW][j] = hnew;                                                     \
        if (MODE < 2) *pSt = hnew;                                              \
    }                                                                           \
    pSt += H;                                                                   \
    LDS_BARRIER();                                                              \
  }

// Run one layer's full 1024-step recurrence. Weights already in VGPRs.
template <int MODE>
__device__ __forceinline__ float run_layer(
    const float* __restrict__ xin,   // MODE0: raw x row; else actb
    float* __restrict__ actb,        // store target (MODE<2)
    float (*hbuf)[H],
    const float4 (&wIv)[3][4], const float4 (&wHv)[3][4],
    float bR, float bZ, float bNi, float bNh,
    int j, int k0, int ks, int bpaddr)
{
    float hprev = 0.0f;
    if (ks == 0) hbuf[0][j] = 0.0f;   // h0 = 0

    float4 xA0, xA1, xA2, xA3, xB0, xB1, xB2, xB3;
    xA0 = xA1 = xA2 = xA3 = make_float4(0.f, 0.f, 0.f, 0.f);
    xB0 = xB1 = xB2 = xB3 = xA0;

    const float* pPFA;
    const float* pPFB;
    if (MODE == 0) {
        if (ks == 0) {
            const float* p0 = xin;        // t=0
            const float* p1 = xin + 5;    // t=1
            xA0 = make_float4(p0[0], p0[1], p0[2], p0[3]); xA1.x = p0[4];
            xB0 = make_float4(p1[0], p1[1], p1[2], p1[3]); xB1.x = p1[4];
        }
        pPFA = xin + 10;                  // t=2 (A holds even t)
        pPFB = xin + 15;                  // t=3 (B holds odd t)
    } else {
        const float4* a0 = (const float4*)(xin + 0 * H + k0);
        const float4* a1 = (const float4*)(xin + 1 * H + k0);
        xA0 = a0[0]; xA1 = a0[1]; xA2 = a0[2]; xA3 = a0[3];
        xB0 = a1[0]; xB1 = a1[1]; xB2 = a1[2]; xB3 = a1[3];
        pPFA = xin + 2 * H + k0;
        pPFB = xin + 3 * H + k0;
    }
    float* pSt = actb + j;

    // Layer boundary: FULL drain (prev layer's act stores -> this layer's
    // reads; hbuf init visibility). Once per layer — cheap.
    __syncthreads();

    for (int t = 0; t < SEQ_T; t += 2) {
        GRU_STEP(xA0, xA1, xA2, xA3, 0, 1, t,     pPFA)
        GRU_STEP(xB0, xB1, xB2, xB3, 1, 0, t + 1, pPFB)
    }
    return hprev;
}

__global__ __launch_bounds__(NTHR, 2) void gru_all_kernel(
    const float* __restrict__ x,
    const float* __restrict__ w_ih0, const float* __restrict__ w_hh0,
    const float* __restrict__ b_ih0, const float* __restrict__ b_hh0,
    const float* __restrict__ w_ih, const float* __restrict__ w_hh,
    const float* __restrict__ b_ih, const float* __restrict__ b_hh,
    const float* __restrict__ w_fc, const float* __restrict__ b_fc,
    float* __restrict__ out, float* __restrict__ act)
{
    __shared__ __align__(16) float hbuf[2][H];  // double-buffered hidden state
    __shared__ float partial[4];

    const int tid  = threadIdx.x;
    const int wv   = tid >> 6;        // wave 0..3
    const int lane = tid & 63;
    const int jl   = lane & 15;
    const int ks   = lane >> 4;       // k-slice 0..3 (k in [16ks, 16ks+16))
    const int j    = wv * 16 + jl;    // output h-index
    const int k0   = ks * 16;
    const int b    = blockIdx.x;
    const int bpaddr = (lane ^ 32) << 2;   // hoisted ds_bpermute byte address

    float* __restrict__ actb = act + (size_t)b * (SEQ_T * H);
    const float* __restrict__ xb = x + (size_t)b * (SEQ_T * 5);

    float hlast = 0.0f;
    float4 wIv[3][4], wHv[3][4];

    for (int layer = 0; layer < 5; ++layer) {
        // ---- weight slices -> VGPRs, ONCE per layer ----
        {
            const float* whp = (layer == 0) ? w_hh0 : w_hh + (size_t)(layer - 1) * (192 * H);
            #pragma unroll
            for (int g = 0; g < 3; ++g) {
                const float4* row = (const float4*)(whp + (g * 64 + j) * H + k0);
                #pragma unroll
                for (int q = 0; q < 4; ++q) wHv[g][q] = row[q];
            }
            if (layer == 0) {
                #pragma unroll
                for (int g = 0; g < 3; ++g)
                    #pragma unroll
                    for (int q = 0; q < 4; ++q) wIv[g][q] = make_float4(0.f, 0.f, 0.f, 0.f);
                if (ks == 0) {
                    #pragma unroll
                    for (int g = 0; g < 3; ++g) {
                        const float* row = w_ih0 + (g * 64 + j) * 5;
                        wIv[g][0] = make_float4(row[0], row[1], row[2], row[3]);
                        wIv[g][1].x = row[4];
                    }
                    // re-pack gate-2 (n) to the slots GRU_STEP MODE0 reads:
                    // an uses wIv[2][0].xyz (k0..2), wIv[2][1].x (k3), wIv[2][1].y (k4)
                    const float* row2 = w_ih0 + (2 * 64 + j) * 5;
                    wIv[2][0] = make_float4(row2[0], row2[1], row2[2], 0.f);
                    wIv[2][1].x = row2[3];
                    wIv[2][1].y = row2[4];
                }
            } else {
                const float* wip = w_ih + (size_t)(layer - 1) * (192 * H);
                #pragma unroll
                for (int g = 0; g < 3; ++g) {
                    const float4* row = (const float4*)(wip + (g * 64 + j) * H + k0);
                    #pragma unroll
                    for (int q = 0; q < 4; ++q) wIv[g][q] = row[q];
                }
            }
        }

        // biases (r/z input+hidden pre-summed; n-gate parts stay separate)
        float bR, bZ, bNi, bNh;
        {
            const float* bip = (layer == 0) ? b_ih0 : b_ih + (layer - 1) * 192;
            const float* bhp = (layer == 0) ? b_hh0 : b_hh + (layer - 1) * 192;
            bR  = bip[j] + bhp[j];
            bZ  = bip[j + 64] + bhp[j + 64];
            bNi = bip[j + 128];
            bNh = bhp[j + 128];
        }

        if (layer == 0)
            hlast = run_layer<0>(xb, actb, hbuf, wIv, wHv, bR, bZ, bNi, bNh, j, k0, ks, bpaddr);
        else if (layer < 4)
            hlast = run_layer<1>(actb, actb, hbuf, wIv, wHv, bR, bZ, bNi, bNh, j, k0, ks, bpaddr);
        else
            hlast = run_layer<2>(actb, actb, hbuf, wIv, wHv, bR, bZ, bNi, bNh, j, k0, ks, bpaddr);
    }

    // ---- fused FC on last timestep: out[b] = h . w_fc + b_fc ----
    float v = (ks == 0) ? hlast * w_fc[j] : 0.0f;
    v += __shfl_xor(v, 1, 64);
    v += __shfl_xor(v, 2, 64);
    v += __shfl_xor(v, 4, 64);
    v += __shfl_xor(v, 8, 64);
    if (lane == 0) partial[wv] = v;
    __syncthreads();
    if (tid == 0) out[b] = partial[0] + partial[1] + partial[2] + partial[3] + b_fc[0];
}

extern "C" void kernel_launch(void* const* d_in, const int* in_sizes, int n_in,
                              void* d_out, int out_size, void* d_ws, size_t ws_size,
                              hipStream_t stream) {
    const float* x     = (const float*)d_in[0];
    const float* w_ih0 = (const float*)d_in[1];
    const float* w_hh0 = (const float*)d_in[2];
    const float* b_ih0 = (const float*)d_in[3];
    const float* b_hh0 = (const float*)d_in[4];
    const float* w_ih  = (const float*)d_in[5];
    const float* w_hh  = (const float*)d_in[6];
    const float* b_ih  = (const float*)d_in[7];
    const float* b_hh  = (const float*)d_in[8];
    const float* w_fc  = (const float*)d_in[9];
    const float* b_fc  = (const float*)d_in[10];
    float* out = (float*)d_out;
    float* act = (float*)d_ws;  // [BATCH][SEQ_T][H] fp32 = 128 MiB

    hipLaunchKernelGGL(gru_all_kernel, dim3(NBLK), dim3(NTHR), 0, stream,
                       x, w_ih0, w_hh0, b_ih0, b_hh0,
                       w_ih, w_hh, b_ih, b_hh, w_fc, b_fc, out, act);
}